// Round 1
// baseline (833.224 us; speedup 1.0000x reference)
//
#include <hip/hip_runtime.h>

// Fp8Padding: multi-segment row copy with 16-row-aligned zero padding.
// M_SPLITS = [8191,8190,8185,8200,8100,8216,8177,8193]
// padded   = [8192,8192,8192,8208,8112,8224,8192,8208], total out rows 65520
// IN_FEATURES = 2048 fp32 -> 512 float4 per row.
//
// R1: persistent grid-stride streaming copy (2048 blocks x 256 thr = 32 waves/CU)
//     + nontemporal load/store hints. Replaces 65520 short-lived one-row blocks.

typedef float f4 __attribute__((ext_vector_type(4)));

#define N_SEG 8
#define ROW_F4 512                     // 2048 floats / 4
#define OUT_ROWS 65520
#define TOTAL_F4 (OUT_ROWS * ROW_F4)   // 33,546,240 float4 elements
#define NBLK 2048                      // 256 CU x 8 blocks/CU
#define NTHR 256

__global__ __launch_bounds__(NTHR, 8) void pad_copy_kernel(
    const f4* __restrict__ inp, f4* __restrict__ out) {
    // Compile-time segment tables.
    const int cum_pad[N_SEG + 1] = {0, 8192, 16384, 24576, 32784, 40896, 49120, 57312, 65520};
    const int cum_in[N_SEG]      = {0, 8191, 16381, 24566, 32766, 40866, 49082, 57259};
    const int mseg[N_SEG]        = {8191, 8190, 8185, 8200, 8100, 8216, 8177, 8193};

    const int stride = NBLK * NTHR;    // 524,288 -> 64 grid-stride iterations
    for (int idx = blockIdx.x * NTHR + threadIdx.x; idx < TOTAL_F4; idx += stride) {
        const int row = idx >> 9;      // output row
        const int c   = idx & 511;     // float4 column within row

        // Segment lookup: 7 compares, branch-free.
        int seg = 0;
#pragma unroll
        for (int i = 1; i < N_SEG; ++i) seg += (row >= cum_pad[i]);

        const int j = row - cum_pad[seg];          // row within segment
        f4 v = (f4){0.f, 0.f, 0.f, 0.f};
        if (j < mseg[seg]) {                       // valid (non-pad) row
            const int src = (cum_in[seg] + j) * ROW_F4 + c;
            v = __builtin_nontemporal_load(inp + src);
        }
        __builtin_nontemporal_store(v, out + idx);
    }
}

extern "C" void kernel_launch(void* const* d_in, const int* in_sizes, int n_in,
                              void* d_out, int out_size, void* d_ws, size_t ws_size,
                              hipStream_t stream) {
    const f4* inp = (const f4*)d_in[0];   // (65452, 2048) fp32
    f4* out = (f4*)d_out;                 // (65520, 2048) fp32
    (void)in_sizes; (void)n_in; (void)d_ws; (void)ws_size; (void)out_size;

    pad_copy_kernel<<<NBLK, NTHR, 0, stream>>>(inp, out);
}